// Round 1
// baseline (629.248 us; speedup 1.0000x reference)
//
#include <hip/hip_runtime.h>
#include <hip/hip_bf16.h>
#include <stdint.h>

// ---------------- types / helpers ----------------
typedef __bf16 bf16x8 __attribute__((ext_vector_type(8)));
typedef unsigned short u16x8 __attribute__((ext_vector_type(8)));
typedef float f32x4 __attribute__((ext_vector_type(4)));

#define DMODEL 768
#define NSEQ   2048
#define BATCH  2
#define NHEAD  12
#define HDIM   64
#define HIDDEN 3072
#define SCALE_F 0.125f   // 64^-0.5

__device__ __forceinline__ uint16_t f2bf(float f) {
  __hip_bfloat16 h = __float2bfloat16(f);
  return __builtin_bit_cast(uint16_t, h);
}
__device__ __forceinline__ bf16x8 ldb8(const uint16_t* p) {
  return __builtin_bit_cast(bf16x8, *reinterpret_cast<const u16x8*>(p));
}

// ---------------- fp32 -> bf16 cast ----------------
__global__ __launch_bounds__(256) void cvt_kernel(const float* __restrict__ in,
                                                  uint16_t* __restrict__ out, int n) {
  int i4 = (blockIdx.x * 256 + threadIdx.x) * 4;
  if (i4 + 3 < n) {
    float4 v = *reinterpret_cast<const float4*>(in + i4);
    ushort4 o;
    o.x = f2bf(v.x); o.y = f2bf(v.y); o.z = f2bf(v.z); o.w = f2bf(v.w);
    *reinterpret_cast<ushort4*>(out + i4) = o;
  }
}

// ---------------- qkv bias assembly ----------------
__global__ __launch_bounds__(256) void bias_kernel(const float* __restrict__ qb,
                                                   const float* __restrict__ vb,
                                                   float* __restrict__ out) {
  int j = blockIdx.x * 256 + threadIdx.x;
  if (j < 3 * DMODEL) {
    float v = 0.f;
    if (j < DMODEL) v = qb[j];
    else if (j >= 2 * DMODEL) v = vb[j - 2 * DMODEL];
    out[j] = v;
  }
}

// ---------------- layernorm: fp32 in -> bf16 out ----------------
__global__ __launch_bounds__(256) void ln_kernel(const float* __restrict__ x,
                                                 const float* __restrict__ g,
                                                 const float* __restrict__ bt,
                                                 uint16_t* __restrict__ out) {
  const int row = blockIdx.x;
  const int t = threadIdx.x;
  const float* xr = x + (size_t)row * DMODEL;
  float v0 = xr[t], v1 = xr[t + 256], v2 = xr[t + 512];
  float s = v0 + v1 + v2;
  float q = v0 * v0 + v1 * v1 + v2 * v2;
  for (int off = 32; off >= 1; off >>= 1) {
    s += __shfl_xor(s, off);
    q += __shfl_xor(q, off);
  }
  __shared__ float ss[4], sq[4];
  int w = t >> 6;
  if ((t & 63) == 0) { ss[w] = s; sq[w] = q; }
  __syncthreads();
  s = ss[0] + ss[1] + ss[2] + ss[3];
  q = sq[0] + sq[1] + sq[2] + sq[3];
  const float mean = s * (1.0f / DMODEL);
  const float var = q * (1.0f / DMODEL) - mean * mean;
  const float rstd = rsqrtf(var + 1e-5f);
  uint16_t* orow = out + (size_t)row * DMODEL;
  orow[t]       = f2bf((v0 - mean) * rstd * g[t]       + bt[t]);
  orow[t + 256] = f2bf((v1 - mean) * rstd * g[t + 256] + bt[t + 256]);
  orow[t + 512] = f2bf((v2 - mean) * rstd * g[t + 512] + bt[t + 512]);
}

// ---------------- GEMM: C[M,N] = A[M,K] * W[N,K]^T + bias, fused epilogues -----
// MODE 0: out bf16 = acc + bias                     (qkv)
// MODE 1: out f32  = resid + gamma*(acc+bias)       (proj + residual1)
// MODE 2: out bf16 = gelu(acc + bias)               (fc1)
// MODE 3: out f32  = resid + gamma*(acc+bias)       (fc2 + residual2, to d_out)
template <int MODE>
__global__ __launch_bounds__(256) void gemm_bt(const uint16_t* __restrict__ A,
                                               const uint16_t* __restrict__ W,
                                               const float* __restrict__ bias,
                                               void* __restrict__ outp,
                                               const float* __restrict__ resid,
                                               const float* __restrict__ gamma,
                                               int M, int N, int K) {
  const int tid = threadIdx.x;
  const int lane = tid & 63;
  const int w = tid >> 6;
  const int wr = w >> 1, wc = w & 1;
  const int r0 = blockIdx.y * 64 + wr * 32;
  const int c0 = blockIdx.x * 64 + wc * 32;
  const int lr = lane & 15;
  const int lk = (lane >> 4) * 8;

  const uint16_t* ap = A + (size_t)(r0 + lr) * K + lk;
  const uint16_t* bp = W + (size_t)(c0 + lr) * K + lk;
  const size_t rowK = (size_t)16 * K;

  f32x4 acc[2][2] = {};
  for (int k0 = 0; k0 < K; k0 += 32) {
    bf16x8 a0 = ldb8(ap + k0);
    bf16x8 a1 = ldb8(ap + rowK + k0);
    bf16x8 b0 = ldb8(bp + k0);
    bf16x8 b1 = ldb8(bp + rowK + k0);
    acc[0][0] = __builtin_amdgcn_mfma_f32_16x16x32_bf16(a0, b0, acc[0][0], 0, 0, 0);
    acc[0][1] = __builtin_amdgcn_mfma_f32_16x16x32_bf16(a0, b1, acc[0][1], 0, 0, 0);
    acc[1][0] = __builtin_amdgcn_mfma_f32_16x16x32_bf16(a1, b0, acc[1][0], 0, 0, 0);
    acc[1][1] = __builtin_amdgcn_mfma_f32_16x16x32_bf16(a1, b1, acc[1][1], 0, 0, 0);
  }
  const int rr = (lane >> 4) * 4;
  for (int i = 0; i < 2; ++i)
    for (int j = 0; j < 2; ++j)
      for (int r = 0; r < 4; ++r) {
        int row = r0 + i * 16 + rr + r;
        int col = c0 + j * 16 + lr;
        float val = acc[i][j][r] + bias[col];
        if constexpr (MODE == 0) {
          ((uint16_t*)outp)[(size_t)row * N + col] = f2bf(val);
        } else if constexpr (MODE == 2) {
          float ge = 0.5f * val * (1.0f + erff(val * 0.70710678118654752f));
          ((uint16_t*)outp)[(size_t)row * N + col] = f2bf(ge);
        } else {
          float v = resid[(size_t)row * N + col] + gamma[col] * val;
          ((float*)outp)[(size_t)row * N + col] = v;
        }
      }
}

// ---------------- V transpose: qkv -> vt[bh][d][n] ----------------
__global__ __launch_bounds__(256) void vtrans_kernel(const uint16_t* __restrict__ qkv,
                                                     uint16_t* __restrict__ vt) {
  int gid = blockIdx.x * 256 + threadIdx.x;   // 24*64*2048 total
  int n = gid & 2047;
  int d = (gid >> 11) & 63;
  int bh = gid >> 17;
  int b = bh / NHEAD, h = bh % NHEAD;
  vt[gid] = qkv[(size_t)(b * NSEQ + n) * (3 * DMODEL) + 2 * DMODEL + h * HDIM + d];
}

// ---------------- flash attention ----------------
// grid: (B*H, N/64); block 256 = 4 waves; each wave owns a 16-row Q tile.
__global__ __launch_bounds__(256) void attn_kernel(const uint16_t* __restrict__ qkv,
                                                   const uint16_t* __restrict__ vt,
                                                   const int* __restrict__ mask,
                                                   uint16_t* __restrict__ o) {
  __shared__ __align__(16) uint16_t plds[4][16][40];  // padded stride 40 (2-way max)
  const int tid = threadIdx.x;
  const int lane = tid & 63;
  const int w = tid >> 6;
  const int bh = blockIdx.x;
  const int b = bh / NHEAD, h = bh % NHEAD;
  const int q0 = blockIdx.y * 64 + w * 16;
  const int lr = lane & 15;
  const int lk4 = lane >> 4;
  const int lk = lk4 * 8;

  const uint16_t* qb = qkv + (size_t)(b * NSEQ + q0 + lr) * (3 * DMODEL) + h * HDIM + lk;
  bf16x8 qa0 = ldb8(qb);
  bf16x8 qa1 = ldb8(qb + 32);

  const uint16_t* kb = qkv + (size_t)(b * NSEQ) * (3 * DMODEL) + DMODEL + h * HDIM + lk;
  const uint16_t* vb = vt + (size_t)bh * HDIM * NSEQ;
  const int* mb = mask + b * NSEQ;

  float m[4] = {-INFINITY, -INFINITY, -INFINITY, -INFINITY};
  float lsum[4] = {0.f, 0.f, 0.f, 0.f};
  f32x4 oacc[4] = {};

  for (int k0 = 0; k0 < NSEQ; k0 += 32) {
    const uint16_t* kp0 = kb + (size_t)(k0 + lr) * (3 * DMODEL);
    const uint16_t* kp1 = kb + (size_t)(k0 + 16 + lr) * (3 * DMODEL);
    f32x4 s0 = {}, s1 = {};
    s0 = __builtin_amdgcn_mfma_f32_16x16x32_bf16(qa0, ldb8(kp0), s0, 0, 0, 0);
    s0 = __builtin_amdgcn_mfma_f32_16x16x32_bf16(qa1, ldb8(kp0 + 32), s0, 0, 0, 0);
    s1 = __builtin_amdgcn_mfma_f32_16x16x32_bf16(qa0, ldb8(kp1), s1, 0, 0, 0);
    s1 = __builtin_amdgcn_mfma_f32_16x16x32_bf16(qa1, ldb8(kp1 + 32), s1, 0, 0, 0);

    const bool msk0 = (mb[k0 + lr] == 0);
    const bool msk1 = (mb[k0 + 16 + lr] == 0);

    float alpha[4], p0[4], p1[4];
    for (int r = 0; r < 4; ++r) {
      float sv0 = msk0 ? -INFINITY : s0[r] * SCALE_F;
      float sv1 = msk1 ? -INFINITY : s1[r] * SCALE_F;
      float t = fmaxf(sv0, sv1);
      t = fmaxf(t, __shfl_xor(t, 1));
      t = fmaxf(t, __shfl_xor(t, 2));
      t = fmaxf(t, __shfl_xor(t, 4));
      t = fmaxf(t, __shfl_xor(t, 8));
      float mnew = fmaxf(m[r], t);
      alpha[r] = (m[r] == -INFINITY) ? 0.f : __expf(m[r] - mnew);
      p0[r] = msk0 ? 0.f : __expf(sv0 - mnew);
      p1[r] = msk1 ? 0.f : __expf(sv1 - mnew);
      float rs = p0[r] + p1[r];
      rs += __shfl_xor(rs, 1);
      rs += __shfl_xor(rs, 2);
      rs += __shfl_xor(rs, 4);
      rs += __shfl_xor(rs, 8);
      lsum[r] = lsum[r] * alpha[r] + rs;
      m[r] = mnew;
    }
    for (int dt = 0; dt < 4; ++dt) {
      f32x4 t = oacc[dt];
      for (int r = 0; r < 4; ++r) t[r] *= alpha[r];
      oacc[dt] = t;
    }
    __syncthreads();
    for (int r = 0; r < 4; ++r) {
      plds[w][lk4 * 4 + r][lr]      = f2bf(p0[r]);
      plds[w][lk4 * 4 + r][16 + lr] = f2bf(p1[r]);
    }
    __syncthreads();
    bf16x8 pa = ldb8(&plds[w][lr][lk]);
    for (int dt = 0; dt < 4; ++dt) {
      const uint16_t* vp = vb + (size_t)(dt * 16 + lr) * NSEQ + k0 + lk;
      oacc[dt] = __builtin_amdgcn_mfma_f32_16x16x32_bf16(pa, ldb8(vp), oacc[dt], 0, 0, 0);
    }
  }

  float inv[4];
  for (int r = 0; r < 4; ++r) inv[r] = lsum[r] > 0.f ? 1.f / lsum[r] : 0.f;
  uint16_t* ob = o + (size_t)(b * NSEQ + q0) * DMODEL + h * HDIM;
  for (int dt = 0; dt < 4; ++dt)
    for (int r = 0; r < 4; ++r)
      ob[(size_t)(lk4 * 4 + r) * DMODEL + dt * 16 + lr] = f2bf(oacc[dt][r] * inv[r]);
}

// ---------------- host ----------------
extern "C" void kernel_launch(void* const* d_in, const int* in_sizes, int n_in,
                              void* d_out, int out_size, void* d_ws, size_t ws_size,
                              hipStream_t stream) {
  const float* x      = (const float*)d_in[0];
  const int*   amask  = (const int*)d_in[1];
  const float* ln1_g  = (const float*)d_in[2];
  const float* ln1_b  = (const float*)d_in[3];
  const float* qkv_w  = (const float*)d_in[4];
  const float* q_bias = (const float*)d_in[5];
  const float* v_bias = (const float*)d_in[6];
  const float* proj_w = (const float*)d_in[7];
  const float* proj_b = (const float*)d_in[8];
  const float* ln2_g  = (const float*)d_in[9];
  const float* ln2_b  = (const float*)d_in[10];
  const float* fc1_w  = (const float*)d_in[11];
  const float* fc1_b  = (const float*)d_in[12];
  const float* fc2_w  = (const float*)d_in[13];
  const float* fc2_b  = (const float*)d_in[14];
  const float* g1     = (const float*)d_in[15];
  const float* g2     = (const float*)d_in[16];

  char* ws = (char*)d_ws;
  uint16_t* qkvw_bf = (uint16_t*)(ws + 0);          // 2304x768 bf16
  uint16_t* projw_bf = (uint16_t*)(ws + 3538944);   // 768x768
  uint16_t* fc1w_bf = (uint16_t*)(ws + 4718592);    // 3072x768
  uint16_t* fc2w_bf = (uint16_t*)(ws + 9437184);    // 768x3072
  float*    qkvbias = (float*)(ws + 14155776);      // 2304 f32
  uint16_t* h_bf    = (uint16_t*)(ws + 14164992);   // 4096x768 (ln1 out; reused as ln2 out)
  uint16_t* qkv_bf  = (uint16_t*)(ws + 20456448);   // 4096x2304 (reused as fc1 out 4096x3072)
  uint16_t* vt_bf   = (uint16_t*)(ws + 39330816);   // 24x64x2048 (tail of fc1-out reuse)
  uint16_t* o_bf    = (uint16_t*)(ws + 45622272);   // 4096x768
  float*    x1_f    = (float*)(ws + 51913728);      // 4096x768 f32
  uint16_t* fc1_bf  = qkv_bf;                       // alias (qkv/vt dead by then)
  uint16_t* h2_bf   = h_bf;                         // alias

  const int M = BATCH * NSEQ;  // 4096

  // weight casts
  cvt_kernel<<<(3 * DMODEL * DMODEL) / 1024, 256, 0, stream>>>(qkv_w, qkvw_bf, 3 * DMODEL * DMODEL);
  cvt_kernel<<<(DMODEL * DMODEL) / 1024, 256, 0, stream>>>(proj_w, projw_bf, DMODEL * DMODEL);
  cvt_kernel<<<(HIDDEN * DMODEL) / 1024, 256, 0, stream>>>(fc1_w, fc1w_bf, HIDDEN * DMODEL);
  cvt_kernel<<<(DMODEL * HIDDEN) / 1024, 256, 0, stream>>>(fc2_w, fc2w_bf, DMODEL * HIDDEN);
  bias_kernel<<<(3 * DMODEL + 255) / 256, 256, 0, stream>>>(q_bias, v_bias, qkvbias);

  // ln1
  ln_kernel<<<M, 256, 0, stream>>>(x, ln1_g, ln1_b, h_bf);
  // qkv gemm
  gemm_bt<0><<<dim3((3 * DMODEL) / 64, M / 64), 256, 0, stream>>>(
      h_bf, qkvw_bf, qkvbias, qkv_bf, nullptr, nullptr, M, 3 * DMODEL, DMODEL);
  // v transpose
  vtrans_kernel<<<(BATCH * NHEAD * HDIM * NSEQ) / 256, 256, 0, stream>>>(qkv_bf, vt_bf);
  // attention
  attn_kernel<<<dim3(BATCH * NHEAD, NSEQ / 64), 256, 0, stream>>>(qkv_bf, vt_bf, amask, o_bf);
  // proj + residual1 -> x1 (f32)
  gemm_bt<1><<<dim3(DMODEL / 64, M / 64), 256, 0, stream>>>(
      o_bf, projw_bf, proj_b, x1_f, x, g1, M, DMODEL, DMODEL);
  // ln2
  ln_kernel<<<M, 256, 0, stream>>>(x1_f, ln2_g, ln2_b, h2_bf);
  // fc1 + gelu
  gemm_bt<2><<<dim3(HIDDEN / 64, M / 64), 256, 0, stream>>>(
      h2_bf, fc1w_bf, fc1_b, fc1_bf, nullptr, nullptr, M, HIDDEN, DMODEL);
  // fc2 + residual2 -> d_out (f32)
  gemm_bt<3><<<dim3(DMODEL / 64, M / 64), 256, 0, stream>>>(
      fc1_bf, fc2w_bf, fc2_b, (float*)d_out, x1_f, g2, M, DMODEL, HIDDEN);
}

// Round 2
// 394.427 us; speedup vs baseline: 1.5953x; 1.5953x over previous
//
#include <hip/hip_runtime.h>
#include <hip/hip_bf16.h>
#include <stdint.h>

// ---------------- types / helpers ----------------
typedef __bf16 bf16x8 __attribute__((ext_vector_type(8)));
typedef unsigned short u16x8 __attribute__((ext_vector_type(8)));
typedef float f32x4 __attribute__((ext_vector_type(4)));

#define DMODEL 768
#define NSEQ   2048
#define BATCH  2
#define NHEAD  12
#define HDIM   64
#define HIDDEN 3072

__device__ __forceinline__ uint16_t f2bf(float f) {
  __hip_bfloat16 h = __float2bfloat16(f);
  return __builtin_bit_cast(uint16_t, h);
}
__device__ __forceinline__ bf16x8 ldb8(const uint16_t* p) {
  return __builtin_bit_cast(bf16x8, *reinterpret_cast<const u16x8*>(p));
}

using as1_void = __attribute__((address_space(1))) const void;
using as3_void = __attribute__((address_space(3))) void;
// global -> LDS direct, 16B per lane; lds dest is wave-uniform base + lane*16
__device__ __forceinline__ void gload16(const uint16_t* src, uint16_t* lds) {
  __builtin_amdgcn_global_load_lds((as1_void*)src, (as3_void*)lds, 16, 0, 0);
}

// ---------------- fused fp32 -> bf16 casts (all 4 weights in one kernel) ------
#define N_QKVW  (3 * DMODEL * DMODEL)            // 1769472
#define N_PROJW (DMODEL * DMODEL)                //  589824
#define N_FC1W  (HIDDEN * DMODEL)                // 2359296
#define N_FC2W  (DMODEL * HIDDEN)                // 2359296
__global__ __launch_bounds__(256) void cvt4_kernel(const float* __restrict__ s0,
                                                   const float* __restrict__ s1,
                                                   const float* __restrict__ s2,
                                                   const float* __restrict__ s3,
                                                   uint16_t* __restrict__ d0,
                                                   uint16_t* __restrict__ d1,
                                                   uint16_t* __restrict__ d2,
                                                   uint16_t* __restrict__ d3) {
  int i4 = (blockIdx.x * 256 + threadIdx.x) * 4;
  const float* s;
  uint16_t* d;
  if (i4 < N_QKVW) { s = s0 + i4; d = d0 + i4; }
  else if (i4 < N_QKVW + N_PROJW) { int j = i4 - N_QKVW; s = s1 + j; d = d1 + j; }
  else if (i4 < N_QKVW + N_PROJW + N_FC1W) { int j = i4 - N_QKVW - N_PROJW; s = s2 + j; d = d2 + j; }
  else { int j = i4 - N_QKVW - N_PROJW - N_FC1W; s = s3 + j; d = d3 + j; }
  float4 v = *reinterpret_cast<const float4*>(s);
  ushort4 o;
  o.x = f2bf(v.x); o.y = f2bf(v.y); o.z = f2bf(v.z); o.w = f2bf(v.w);
  *reinterpret_cast<ushort4*>(d) = o;
}

// ---------------- qkv bias assembly ----------------
__global__ __launch_bounds__(256) void bias_kernel(const float* __restrict__ qb,
                                                   const float* __restrict__ vb,
                                                   float* __restrict__ out) {
  int j = blockIdx.x * 256 + threadIdx.x;
  if (j < 3 * DMODEL) {
    float v = 0.f;
    if (j < DMODEL) v = qb[j];
    else if (j >= 2 * DMODEL) v = vb[j - 2 * DMODEL];
    out[j] = v;
  }
}

// ---------------- layernorm: fp32 in -> bf16 out ----------------
__global__ __launch_bounds__(256) void ln_kernel(const float* __restrict__ x,
                                                 const float* __restrict__ g,
                                                 const float* __restrict__ bt,
                                                 uint16_t* __restrict__ out) {
  const int row = blockIdx.x;
  const int t = threadIdx.x;
  const float* xr = x + (size_t)row * DMODEL;
  float v0 = xr[t], v1 = xr[t + 256], v2 = xr[t + 512];
  float s = v0 + v1 + v2;
  float q = v0 * v0 + v1 * v1 + v2 * v2;
  for (int off = 32; off >= 1; off >>= 1) {
    s += __shfl_xor(s, off);
    q += __shfl_xor(q, off);
  }
  __shared__ float ss[4], sq[4];
  int w = t >> 6;
  if ((t & 63) == 0) { ss[w] = s; sq[w] = q; }
  __syncthreads();
  s = ss[0] + ss[1] + ss[2] + ss[3];
  q = sq[0] + sq[1] + sq[2] + sq[3];
  const float mean = s * (1.0f / DMODEL);
  const float var = q * (1.0f / DMODEL) - mean * mean;
  const float rstd = rsqrtf(var + 1e-5f);
  uint16_t* orow = out + (size_t)row * DMODEL;
  orow[t]       = f2bf((v0 - mean) * rstd * g[t]       + bt[t]);
  orow[t + 256] = f2bf((v1 - mean) * rstd * g[t + 256] + bt[t + 256]);
  orow[t + 512] = f2bf((v2 - mean) * rstd * g[t + 512] + bt[t + 512]);
}

// ---------------- GEMM (m97 structure): C[M,N] = A[M,K] * W[N,K]^T + bias ------
// 128x128 tile, BK=32, global_load_lds(16B) staging, 4 waves x (64x64) output.
// MODE 0: out bf16 = acc + bias; q-columns (col<DMODEL) pre-scaled by 0.125 (qkv)
// MODE 1: out f32  = resid + gamma*(acc+bias)       (proj + residual1)
// MODE 2: out bf16 = gelu(acc + bias)               (fc1)
// MODE 3: out f32  = resid + gamma*(acc+bias)       (fc2 + residual2, to d_out)
template <int MODE>
__global__ __launch_bounds__(256) void gemm128(const uint16_t* __restrict__ A,
                                               const uint16_t* __restrict__ W,
                                               const float* __restrict__ bias,
                                               void* __restrict__ outp,
                                               const float* __restrict__ resid,
                                               const float* __restrict__ gamma,
                                               int M, int N, int K) {
  __shared__ uint16_t As[128 * 32];   // [row][k] row-major, 64B rows
  __shared__ uint16_t Bs[128 * 32];
  const int tid = threadIdx.x;
  const int lane = tid & 63;
  const int w = tid >> 6;
  const int wr = w >> 1, wc = w & 1;
  const int row0 = blockIdx.y * 128;
  const int col0 = blockIdx.x * 128;
  const int lr = lane & 15;
  const int g = lane >> 4;

  // staging geometry: tile = 8KB; wave w + issue i covers bytes [(i*4+w)*1024, +1024)
  const int o0 = w * 1024 + lane * 16;            // this lane's byte offset, issue 0
  const int o1 = o0 + 4096;                       // issue 1
  const int r0s = o0 >> 6, c0s = (o0 & 63) >> 1;  // tile row / k-col (elements)
  const int r1s = o1 >> 6, c1s = (o1 & 63) >> 1;
  uint16_t* lA0 = As + ((w * 1024) >> 1);         // wave-uniform LDS dests
  uint16_t* lA1 = As + ((w * 1024 + 4096) >> 1);
  uint16_t* lB0 = Bs + ((w * 1024) >> 1);
  uint16_t* lB1 = Bs + ((w * 1024 + 4096) >> 1);
  const uint16_t* Abase = A + (size_t)row0 * K;
  const uint16_t* Wbase = W + (size_t)col0 * K;

  f32x4 acc[4][4] = {};
  for (int k0 = 0; k0 < K; k0 += 32) {
    gload16(Abase + (size_t)r0s * K + k0 + c0s, lA0);
    gload16(Abase + (size_t)r1s * K + k0 + c1s, lA1);
    gload16(Wbase + (size_t)r0s * K + k0 + c0s, lB0);
    gload16(Wbase + (size_t)r1s * K + k0 + c1s, lB1);
    __syncthreads();   // compiler emits vmcnt(0) drain before barrier
    bf16x8 a[4], b[4];
#pragma unroll
    for (int m = 0; m < 4; ++m) a[m] = ldb8(As + (wr * 64 + m * 16 + lr) * 32 + g * 8);
#pragma unroll
    for (int n = 0; n < 4; ++n) b[n] = ldb8(Bs + (wc * 64 + n * 16 + lr) * 32 + g * 8);
#pragma unroll
    for (int m = 0; m < 4; ++m)
#pragma unroll
      for (int n = 0; n < 4; ++n)
        acc[m][n] = __builtin_amdgcn_mfma_f32_16x16x32_bf16(a[m], b[n], acc[m][n], 0, 0, 0);
    __syncthreads();
  }

#pragma unroll
  for (int m = 0; m < 4; ++m) {
    int row = row0 + wr * 64 + m * 16 + g * 4;
#pragma unroll
    for (int n = 0; n < 4; ++n) {
      int col = col0 + wc * 64 + n * 16 + lr;
      float bv = bias[col];
#pragma unroll
      for (int ri = 0; ri < 4; ++ri) {
        float val = acc[m][n][ri] + bv;
        size_t idx = (size_t)(row + ri) * N + col;
        if constexpr (MODE == 0) {
          if (col < DMODEL) val *= 0.125f;   // fold attention scale into Q (exact)
          ((uint16_t*)outp)[idx] = f2bf(val);
        } else if constexpr (MODE == 2) {
          float ge = 0.5f * val * (1.0f + erff(val * 0.70710678118654752f));
          ((uint16_t*)outp)[idx] = f2bf(ge);
        } else {
          ((float*)outp)[idx] = resid[idx] + gamma[col] * val;
        }
      }
    }
  }
}

// ---------------- V transpose (LDS-tiled, coalesced): qkv -> vt[bh][d][n] ------
__global__ __launch_bounds__(256) void vtrans_kernel(const uint16_t* __restrict__ qkv,
                                                     uint16_t* __restrict__ vt) {
  __shared__ uint16_t tile[64][72];  // [n][d], padded
  const int t = threadIdx.x;
  const int bh = blockIdx.x;
  const int n0 = blockIdx.y * 64;
  const int b = bh / NHEAD, h = bh % NHEAD;
  const uint16_t* src = qkv + (size_t)(b * NSEQ + n0) * (3 * DMODEL) + 2 * DMODEL + h * HDIM;
#pragma unroll
  for (int it = 0; it < 2; ++it) {
    int slot = it * 256 + t;
    int r = slot >> 2, c = (slot & 3) * 16;
    u16x8 v0 = *reinterpret_cast<const u16x8*>(src + (size_t)r * (3 * DMODEL) + c);
    u16x8 v1 = *reinterpret_cast<const u16x8*>(src + (size_t)r * (3 * DMODEL) + c + 8);
    *reinterpret_cast<u16x8*>(&tile[r][c]) = v0;
    *reinterpret_cast<u16x8*>(&tile[r][c + 8]) = v1;
  }
  __syncthreads();
  uint16_t* dst = vt + (size_t)bh * HDIM * NSEQ + n0;
#pragma unroll
  for (int it = 0; it < 2; ++it) {
    int slot = it * 256 + t;
    int d = slot >> 2, c = (slot & 3) * 16;
    u16x8 a0, a1;
#pragma unroll
    for (int e = 0; e < 8; ++e) a0[e] = tile[c + e][d];
#pragma unroll
    for (int e = 0; e < 8; ++e) a1[e] = tile[c + 8 + e][d];
    *reinterpret_cast<u16x8*>(dst + (size_t)d * NSEQ + c) = a0;
    *reinterpret_cast<u16x8*>(dst + (size_t)d * NSEQ + c + 8) = a1;
  }
}

// ---------------- flash attention ----------------
// grid: (B*H, N/64); block 256 = 4 waves; each wave owns 16 Q rows, KVBLK=64.
// Q pre-scaled by 0.125 in the qkv-GEMM epilogue. No block barriers: the P-tile
// LDS round-trip is per-wave data and same-wave DS ops execute in order.
__global__ __launch_bounds__(256) void attn_kernel(const uint16_t* __restrict__ qkv,
                                                   const uint16_t* __restrict__ vt,
                                                   const int* __restrict__ mask,
                                                   uint16_t* __restrict__ o) {
  __shared__ __align__(16) uint16_t plds[4][16][72];
  const int tid = threadIdx.x;
  const int lane = tid & 63;
  const int w = tid >> 6;
  const int bh = blockIdx.x;
  const int b = bh / NHEAD, h = bh % NHEAD;
  const int q0 = blockIdx.y * 64 + w * 16;
  const int lr = lane & 15;
  const int g = lane >> 4;
  const int lk = g * 8;

  const uint16_t* qb = qkv + (size_t)(b * NSEQ + q0 + lr) * (3 * DMODEL) + h * HDIM + lk;
  bf16x8 qa0 = ldb8(qb);
  bf16x8 qa1 = ldb8(qb + 32);
  const uint16_t* kb = qkv + (size_t)(b * NSEQ) * (3 * DMODEL) + DMODEL + h * HDIM + lk;
  const uint16_t* vb = vt + (size_t)bh * HDIM * NSEQ;
  const int* mb = mask + b * NSEQ;

  float m[4] = {-1e30f, -1e30f, -1e30f, -1e30f};
  float lsum[4] = {0.f, 0.f, 0.f, 0.f};
  f32x4 oacc[4] = {};

  for (int k0 = 0; k0 < NSEQ; k0 += 64) {
    f32x4 st[4];
#pragma unroll
    for (int j = 0; j < 4; ++j) {
      const uint16_t* kp = kb + (size_t)(k0 + j * 16 + lr) * (3 * DMODEL);
      f32x4 s = {};
      s = __builtin_amdgcn_mfma_f32_16x16x32_bf16(qa0, ldb8(kp), s, 0, 0, 0);
      s = __builtin_amdgcn_mfma_f32_16x16x32_bf16(qa1, ldb8(kp + 32), s, 0, 0, 0);
      st[j] = s;
    }
    int mv[4];
#pragma unroll
    for (int j = 0; j < 4; ++j) mv[j] = mb[k0 + j * 16 + lr];

    float sv[4][4], tmax[4];
    float need = -1e30f;
#pragma unroll
    for (int r = 0; r < 4; ++r) {
      float t = -1e30f;
#pragma unroll
      for (int j = 0; j < 4; ++j) {
        float s = mv[j] ? st[j][r] : -1e30f;
        sv[r][j] = s;
        t = fmaxf(t, s);
      }
      t = fmaxf(t, __shfl_xor(t, 1));
      t = fmaxf(t, __shfl_xor(t, 2));
      t = fmaxf(t, __shfl_xor(t, 4));
      t = fmaxf(t, __shfl_xor(t, 8));
      tmax[r] = t;
      need = fmaxf(need, t - m[r]);
    }
    if (__any(need > 8.0f)) {           // defer-max (T13): rescale only on real growth
#pragma unroll
      for (int r = 0; r < 4; ++r) {
        float mn = fmaxf(m[r], tmax[r]);
        float al = __expf(m[r] - mn);
        lsum[r] *= al;
        m[r] = mn;
#pragma unroll
        for (int dt = 0; dt < 4; ++dt) oacc[dt][r] *= al;
      }
    }
#pragma unroll
    for (int r = 0; r < 4; ++r) {
      float rs = 0.f;
#pragma unroll
      for (int j = 0; j < 4; ++j) {
        float pv = mv[j] ? __expf(sv[r][j] - m[r]) : 0.f;
        plds[w][g * 4 + r][j * 16 + lr] = f2bf(pv);
        rs += pv;
      }
      rs += __shfl_xor(rs, 1);
      rs += __shfl_xor(rs, 2);
      rs += __shfl_xor(rs, 4);
      rs += __shfl_xor(rs, 8);
      lsum[r] += rs;
    }
    bf16x8 pa0 = ldb8(&plds[w][lr][lk]);
    bf16x8 pa1 = ldb8(&plds[w][lr][32 + lk]);
#pragma unroll
    for (int dt = 0; dt < 4; ++dt) {
      const uint16_t* vp = vb + (size_t)(dt * 16 + lr) * NSEQ + k0 + lk;
      oacc[dt] = __builtin_amdgcn_mfma_f32_16x16x32_bf16(pa0, ldb8(vp), oacc[dt], 0, 0, 0);
      oacc[dt] = __builtin_amdgcn_mfma_f32_16x16x32_bf16(pa1, ldb8(vp + 32), oacc[dt], 0, 0, 0);
    }
  }

  float inv[4];
#pragma unroll
  for (int r = 0; r < 4; ++r) inv[r] = lsum[r] > 0.f ? 1.f / lsum[r] : 0.f;
  uint16_t* ob = o + (size_t)(b * NSEQ + q0) * DMODEL + h * HDIM;
#pragma unroll
  for (int dt = 0; dt < 4; ++dt)
#pragma unroll
    for (int r = 0; r < 4; ++r)
      ob[(size_t)(g * 4 + r) * DMODEL + dt * 16 + lr] = f2bf(oacc[dt][r] * inv[r]);
}

// ---------------- host ----------------
extern "C" void kernel_launch(void* const* d_in, const int* in_sizes, int n_in,
                              void* d_out, int out_size, void* d_ws, size_t ws_size,
                              hipStream_t stream) {
  const float* x      = (const float*)d_in[0];
  const int*   amask  = (const int*)d_in[1];
  const float* ln1_g  = (const float*)d_in[2];
  const float* ln1_b  = (const float*)d_in[3];
  const float* qkv_w  = (const float*)d_in[4];
  const float* q_bias = (const float*)d_in[5];
  const float* v_bias = (const float*)d_in[6];
  const float* proj_w = (const float*)d_in[7];
  const float* proj_b = (const float*)d_in[8];
  const float* ln2_g  = (const float*)d_in[9];
  const float* ln2_b  = (const float*)d_in[10];
  const float* fc1_w  = (const float*)d_in[11];
  const float* fc1_b  = (const float*)d_in[12];
  const float* fc2_w  = (const float*)d_in[13];
  const float* fc2_b  = (const float*)d_in[14];
  const float* g1     = (const float*)d_in[15];
  const float* g2     = (const float*)d_in[16];

  char* ws = (char*)d_ws;
  uint16_t* qkvw_bf  = (uint16_t*)(ws + 0);          // 2304x768 bf16
  uint16_t* projw_bf = (uint16_t*)(ws + 3538944);    // 768x768
  uint16_t* fc1w_bf  = (uint16_t*)(ws + 4718592);    // 3072x768
  uint16_t* fc2w_bf  = (uint16_t*)(ws + 9437184);    // 768x3072
  float*    qkvbias  = (float*)(ws + 14155776);      // 2304 f32
  uint16_t* h_bf     = (uint16_t*)(ws + 14164992);   // 4096x768 (ln1 out; reused as ln2 out)
  uint16_t* qkv_bf   = (uint16_t*)(ws + 20456448);   // 4096x2304 (reused as fc1 out 4096x3072)
  uint16_t* vt_bf    = (uint16_t*)(ws + 39330816);   // 24x64x2048
  uint16_t* o_bf     = (uint16_t*)(ws + 45622272);   // 4096x768
  float*    x1_f     = (float*)(ws + 51913728);      // 4096x768 f32
  uint16_t* fc1_bf   = qkv_bf;                       // alias (qkv/vt dead by then)
  uint16_t* h2_bf    = h_bf;                         // alias

  const int M = BATCH * NSEQ;  // 4096

  // weight casts (one fused kernel) + bias assembly
  cvt4_kernel<<<(N_QKVW + N_PROJW + N_FC1W + N_FC2W) / 1024, 256, 0, stream>>>(
      qkv_w, proj_w, fc1_w, fc2_w, qkvw_bf, projw_bf, fc1w_bf, fc2w_bf);
  bias_kernel<<<(3 * DMODEL + 255) / 256, 256, 0, stream>>>(q_bias, v_bias, qkvbias);

  // ln1
  ln_kernel<<<M, 256, 0, stream>>>(x, ln1_g, ln1_b, h_bf);
  // qkv gemm (Q columns pre-scaled by 0.125)
  gemm128<0><<<dim3((3 * DMODEL) / 128, M / 128), 256, 0, stream>>>(
      h_bf, qkvw_bf, qkvbias, qkv_bf, nullptr, nullptr, M, 3 * DMODEL, DMODEL);
  // v transpose
  vtrans_kernel<<<dim3(BATCH * NHEAD, NSEQ / 64), 256, 0, stream>>>(qkv_bf, vt_bf);
  // attention
  attn_kernel<<<dim3(BATCH * NHEAD, NSEQ / 64), 256, 0, stream>>>(qkv_bf, vt_bf, amask, o_bf);
  // proj + residual1 -> x1 (f32)
  gemm128<1><<<dim3(DMODEL / 128, M / 128), 256, 0, stream>>>(
      o_bf, projw_bf, proj_b, x1_f, x, g1, M, DMODEL, DMODEL);
  // ln2
  ln_kernel<<<M, 256, 0, stream>>>(x1_f, ln2_g, ln2_b, h2_bf);
  // fc1 + gelu
  gemm128<2><<<dim3(HIDDEN / 128, M / 128), 256, 0, stream>>>(
      h2_bf, fc1w_bf, fc1_b, fc1_bf, nullptr, nullptr, M, HIDDEN, DMODEL);
  // fc2 + residual2 -> d_out (f32)
  gemm128<3><<<dim3(DMODEL / 128, M / 128), 256, 0, stream>>>(
      fc1_bf, fc2w_bf, fc2_b, (float*)d_out, x1_f, g2, M, DMODEL, HIDDEN);
}

// Round 3
// 257.245 us; speedup vs baseline: 2.4461x; 1.5333x over previous
//
#include <hip/hip_runtime.h>
#include <hip/hip_bf16.h>
#include <stdint.h>

// ---------------- types / helpers ----------------
typedef __bf16 bf16x8 __attribute__((ext_vector_type(8)));
typedef unsigned short u16x8 __attribute__((ext_vector_type(8)));
typedef float f32x4 __attribute__((ext_vector_type(4)));

#define DMODEL 768
#define NSEQ   2048
#define BATCH  2
#define NHEAD  12
#define HDIM   64
#define HIDDEN 3072

__device__ __forceinline__ uint16_t f2bf(float f) {
  __hip_bfloat16 h = __float2bfloat16(f);
  return __builtin_bit_cast(uint16_t, h);
}
__device__ __forceinline__ bf16x8 ldb8(const uint16_t* p) {
  return __builtin_bit_cast(bf16x8, *reinterpret_cast<const u16x8*>(p));
}

using as1_void = __attribute__((address_space(1))) const void;
using as3_void = __attribute__((address_space(3))) void;
// global -> LDS direct, 16B per lane; lds dest is wave-uniform base + lane*16
__device__ __forceinline__ void gload16(const uint16_t* src, uint16_t* lds) {
  __builtin_amdgcn_global_load_lds((as1_void*)src, (as3_void*)lds, 16, 0, 0);
}
#define MEMFENCE asm volatile("" ::: "memory")

// ---------------- fused fp32 -> bf16 casts (all 4 weights in one kernel) ------
#define N_QKVW  (3 * DMODEL * DMODEL)
#define N_PROJW (DMODEL * DMODEL)
#define N_FC1W  (HIDDEN * DMODEL)
#define N_FC2W  (DMODEL * HIDDEN)
__global__ __launch_bounds__(256) void cvt4_kernel(const float* __restrict__ s0,
                                                   const float* __restrict__ s1,
                                                   const float* __restrict__ s2,
                                                   const float* __restrict__ s3,
                                                   uint16_t* __restrict__ d0,
                                                   uint16_t* __restrict__ d1,
                                                   uint16_t* __restrict__ d2,
                                                   uint16_t* __restrict__ d3) {
  int i4 = (blockIdx.x * 256 + threadIdx.x) * 4;
  const float* s;
  uint16_t* d;
  if (i4 < N_QKVW) { s = s0 + i4; d = d0 + i4; }
  else if (i4 < N_QKVW + N_PROJW) { int j = i4 - N_QKVW; s = s1 + j; d = d1 + j; }
  else if (i4 < N_QKVW + N_PROJW + N_FC1W) { int j = i4 - N_QKVW - N_PROJW; s = s2 + j; d = d2 + j; }
  else { int j = i4 - N_QKVW - N_PROJW - N_FC1W; s = s3 + j; d = d3 + j; }
  float4 v = *reinterpret_cast<const float4*>(s);
  ushort4 o;
  o.x = f2bf(v.x); o.y = f2bf(v.y); o.z = f2bf(v.z); o.w = f2bf(v.w);
  *reinterpret_cast<ushort4*>(d) = o;
}

// ---------------- qkv bias assembly ----------------
__global__ __launch_bounds__(256) void bias_kernel(const float* __restrict__ qb,
                                                   const float* __restrict__ vb,
                                                   float* __restrict__ out) {
  int j = blockIdx.x * 256 + threadIdx.x;
  if (j < 3 * DMODEL) {
    float v = 0.f;
    if (j < DMODEL) v = qb[j];
    else if (j >= 2 * DMODEL) v = vb[j - 2 * DMODEL];
    out[j] = v;
  }
}

// ---------------- layernorm: fp32 in -> bf16 out ----------------
__global__ __launch_bounds__(256) void ln_kernel(const float* __restrict__ x,
                                                 const float* __restrict__ g,
                                                 const float* __restrict__ bt,
                                                 uint16_t* __restrict__ out) {
  const int row = blockIdx.x;
  const int t = threadIdx.x;
  const float* xr = x + (size_t)row * DMODEL;
  float v0 = xr[t], v1 = xr[t + 256], v2 = xr[t + 512];
  float s = v0 + v1 + v2;
  float q = v0 * v0 + v1 * v1 + v2 * v2;
  for (int off = 32; off >= 1; off >>= 1) {
    s += __shfl_xor(s, off);
    q += __shfl_xor(q, off);
  }
  __shared__ float ss[4], sq[4];
  int w = t >> 6;
  if ((t & 63) == 0) { ss[w] = s; sq[w] = q; }
  __syncthreads();
  s = ss[0] + ss[1] + ss[2] + ss[3];
  q = sq[0] + sq[1] + sq[2] + sq[3];
  const float mean = s * (1.0f / DMODEL);
  const float var = q * (1.0f / DMODEL) - mean * mean;
  const float rstd = rsqrtf(var + 1e-5f);
  uint16_t* orow = out + (size_t)row * DMODEL;
  orow[t]       = f2bf((v0 - mean) * rstd * g[t]       + bt[t]);
  orow[t + 256] = f2bf((v1 - mean) * rstd * g[t + 256] + bt[t + 256]);
  orow[t + 512] = f2bf((v2 - mean) * rstd * g[t + 512] + bt[t + 512]);
}

// ---------------- GEMM: C = A * W^T + bias; 128x128 tile, dbuf counted-vmcnt --
template <int MODE>
__global__ __launch_bounds__(256, 3) void gemm128(const uint16_t* __restrict__ A,
                                                  const uint16_t* __restrict__ W,
                                                  const float* __restrict__ bias,
                                                  void* __restrict__ outp,
                                                  const float* __restrict__ resid,
                                                  const float* __restrict__ gamma,
                                                  int M, int N, int K) {
  __shared__ uint16_t As[2][128 * 32];
  __shared__ uint16_t Bs[2][128 * 32];
  const int tid = threadIdx.x;
  const int lane = tid & 63;
  const int w = tid >> 6;
  const int wr = w >> 1, wc = w & 1;
  const int row0 = blockIdx.y * 128;
  const int col0 = blockIdx.x * 128;
  const int lr = lane & 15;
  const int g = lane >> 4;

  const int o0 = w * 1024 + lane * 16;
  const int o1 = o0 + 4096;
  const int r0s = o0 >> 6, c0s = (o0 & 63) >> 1;
  const int r1s = o1 >> 6, c1s = (o1 & 63) >> 1;
  const int l0 = (w * 1024) >> 1;
  const int l1 = l0 + 2048;
  const uint16_t* Abase = A + (size_t)row0 * K;
  const uint16_t* Wbase = W + (size_t)col0 * K;

  auto stage = [&](int kt) {
    uint16_t* Ad = &As[kt & 1][0];
    uint16_t* Bd = &Bs[kt & 1][0];
    const int kk = kt * 32;
    gload16(Abase + (size_t)r0s * K + kk + c0s, Ad + l0);
    gload16(Abase + (size_t)r1s * K + kk + c1s, Ad + l1);
    gload16(Wbase + (size_t)r0s * K + kk + c0s, Bd + l0);
    gload16(Wbase + (size_t)r1s * K + kk + c1s, Bd + l1);
  };

  f32x4 acc[4][4] = {};
  const int nt = K >> 5;
  stage(0);
  for (int kt = 0; kt < nt; ++kt) {
    if (kt + 1 < nt) {
      stage(kt + 1);
      asm volatile("s_waitcnt vmcnt(4)" ::: "memory");
    } else {
      asm volatile("s_waitcnt vmcnt(0)" ::: "memory");
    }
    __builtin_amdgcn_s_barrier();
    MEMFENCE;
    const uint16_t* Ab = &As[kt & 1][0];
    const uint16_t* Bb = &Bs[kt & 1][0];
    bf16x8 a[4], b[4];
#pragma unroll
    for (int m = 0; m < 4; ++m) a[m] = ldb8(Ab + (wr * 64 + m * 16 + lr) * 32 + g * 8);
#pragma unroll
    for (int n = 0; n < 4; ++n) b[n] = ldb8(Bb + (wc * 64 + n * 16 + lr) * 32 + g * 8);
#pragma unroll
    for (int m = 0; m < 4; ++m)
#pragma unroll
      for (int n = 0; n < 4; ++n)
        acc[m][n] = __builtin_amdgcn_mfma_f32_16x16x32_bf16(a[m], b[n], acc[m][n], 0, 0, 0);
    MEMFENCE;
    __builtin_amdgcn_s_barrier();
  }

#pragma unroll
  for (int m = 0; m < 4; ++m) {
    int row = row0 + wr * 64 + m * 16 + g * 4;
#pragma unroll
    for (int n = 0; n < 4; ++n) {
      int col = col0 + wc * 64 + n * 16 + lr;
      float bv = bias[col];
#pragma unroll
      for (int ri = 0; ri < 4; ++ri) {
        float val = acc[m][n][ri] + bv;
        size_t idx = (size_t)(row + ri) * N + col;
        if constexpr (MODE == 0) {
          if (col < DMODEL) val *= 0.125f;   // fold attention scale into Q (exact)
          ((uint16_t*)outp)[idx] = f2bf(val);
        } else if constexpr (MODE == 2) {
          float ge = 0.5f * val * (1.0f + erff(val * 0.70710678118654752f));
          ((uint16_t*)outp)[idx] = f2bf(ge);
        } else {
          ((float*)outp)[idx] = resid[idx] + gamma[col] * val;
        }
      }
    }
  }
}

// ---------------- V transpose (LDS-tiled, coalesced): qkv -> vt[bh][d][n] ------
__global__ __launch_bounds__(256) void vtrans_kernel(const uint16_t* __restrict__ qkv,
                                                     uint16_t* __restrict__ vt) {
  __shared__ uint16_t tile[64][72];
  const int t = threadIdx.x;
  const int bh = blockIdx.x;
  const int n0 = blockIdx.y * 64;
  const int b = bh / NHEAD, h = bh % NHEAD;
  const uint16_t* src = qkv + (size_t)(b * NSEQ + n0) * (3 * DMODEL) + 2 * DMODEL + h * HDIM;
#pragma unroll
  for (int it = 0; it < 2; ++it) {
    int slot = it * 256 + t;
    int r = slot >> 2, c = (slot & 3) * 16;
    u16x8 v0 = *reinterpret_cast<const u16x8*>(src + (size_t)r * (3 * DMODEL) + c);
    u16x8 v1 = *reinterpret_cast<const u16x8*>(src + (size_t)r * (3 * DMODEL) + c + 8);
    *reinterpret_cast<u16x8*>(&tile[r][c]) = v0;
    *reinterpret_cast<u16x8*>(&tile[r][c + 8]) = v1;
  }
  __syncthreads();
  uint16_t* dst = vt + (size_t)bh * HDIM * NSEQ + n0;
#pragma unroll
  for (int it = 0; it < 2; ++it) {
    int slot = it * 256 + t;
    int d = slot >> 2, c = (slot & 3) * 16;
    u16x8 a0, a1;
#pragma unroll
    for (int e = 0; e < 8; ++e) a0[e] = tile[c + e][d];
#pragma unroll
    for (int e = 0; e < 8; ++e) a1[e] = tile[c + 8 + e][d];
    *reinterpret_cast<u16x8*>(dst + (size_t)d * NSEQ + c) = a0;
    *reinterpret_cast<u16x8*>(dst + (size_t)d * NSEQ + c + 8) = a1;
  }
}

// ---------------- flash attention (LDS-staged K/V, dbuf, counted vmcnt) -------
// grid (B*H, N/64); 4 waves; wave owns 16 q rows. K/V tiles 64x64 bf16 in LDS,
// XOR-swizzled (chunk ^= row&7) via pre-swizzled global source (gload_lds dest
// is linear). Mask folded once into an LDS f32 bias table (0 / -3e30).
__global__ __launch_bounds__(256, 3) void attn_kernel(const uint16_t* __restrict__ qkv,
                                                      const uint16_t* __restrict__ vt,
                                                      const int* __restrict__ mask,
                                                      uint16_t* __restrict__ o) {
  __shared__ uint16_t Kb[2][64 * 64];
  __shared__ uint16_t Vb[2][64 * 64];
  __shared__ __align__(16) uint16_t plds[4][16][72];
  __shared__ float sbias[NSEQ];
  const int tid = threadIdx.x;
  const int lane = tid & 63;
  const int w = tid >> 6;
  const int bh = blockIdx.x;
  const int b = bh / NHEAD, h = bh % NHEAD;
  const int q0 = blockIdx.y * 64 + w * 16;
  const int lr = lane & 15;
  const int g = lane >> 4;
  const int lk = g * 8;

  // one-time mask -> additive bias (masked = -3e30: exp underflows to 0, m stays finite)
  const int* mb = mask + b * NSEQ;
  for (int i = tid; i < NSEQ; i += 256) sbias[i] = mb[i] ? 0.f : -3e30f;

  const uint16_t* qb = qkv + (size_t)(b * NSEQ + q0 + lr) * (3 * DMODEL) + h * HDIM + lk;
  bf16x8 qa0 = ldb8(qb);
  bf16x8 qa1 = ldb8(qb + 32);
  const uint16_t* kglob = qkv + (size_t)b * NSEQ * (3 * DMODEL) + DMODEL + h * HDIM;
  const uint16_t* vtb = vt + (size_t)bh * HDIM * NSEQ;

  __syncthreads();   // sbias visible (before any staging is issued)

  // staging geometry: thread t covers tile byte o = i*4096 + t*16
  const int srow = tid >> 3;                       // + 32*i
  const int sxor = ((tid & 7) ^ ((tid >> 3) & 7)) * 8;   // swizzled source chunk (elems)
  auto stage = [&](int t) {
    const int p = t & 1;
    const int k0 = t * 64;
#pragma unroll
    for (int i = 0; i < 2; ++i) {
      const int row = i * 32 + srow;
      gload16(kglob + (size_t)(k0 + row) * (3 * DMODEL) + sxor, &Kb[p][i * 2048 + w * 512]);
      gload16(vtb + (size_t)row * NSEQ + k0 + sxor, &Vb[p][i * 2048 + w * 512]);
    }
  };
  // swizzled read offsets (elements): chunk g / 4+g, XOR row&7 (= lr&7)
  const int koff0 = ((g ^ (lr & 7))) * 8;
  const int koff1 = (((4 + g) ^ (lr & 7))) * 8;

  float m[4] = {-1e30f, -1e30f, -1e30f, -1e30f};
  float lsum[4] = {0.f, 0.f, 0.f, 0.f};
  f32x4 oacc[4] = {};

  stage(0);
  const int NT = NSEQ / 64;
  for (int t = 0; t < NT; ++t) {
    if (t + 1 < NT) {
      stage(t + 1);
      asm volatile("s_waitcnt vmcnt(4)" ::: "memory");
    } else {
      asm volatile("s_waitcnt vmcnt(0)" ::: "memory");
    }
    __builtin_amdgcn_s_barrier();
    MEMFENCE;
    const uint16_t* Kbp = &Kb[t & 1][0];
    const uint16_t* Vbp = &Vb[t & 1][0];
    const int k0 = t * 64;

    f32x4 st[4];
#pragma unroll
    for (int j = 0; j < 4; ++j) {
      const uint16_t* kr = Kbp + (j * 16 + lr) * 64;
      f32x4 s = {};
      s = __builtin_amdgcn_mfma_f32_16x16x32_bf16(qa0, ldb8(kr + koff0), s, 0, 0, 0);
      s = __builtin_amdgcn_mfma_f32_16x16x32_bf16(qa1, ldb8(kr + koff1), s, 0, 0, 0);
      st[j] = s;
    }
    float bj[4];
#pragma unroll
    for (int j = 0; j < 4; ++j) bj[j] = sbias[k0 + j * 16 + lr];

    float sv[4][4], tmax[4];
    float need = -1e30f;
#pragma unroll
    for (int r = 0; r < 4; ++r) {
      float tm = -1e30f;
#pragma unroll
      for (int j = 0; j < 4; ++j) {
        float s = st[j][r] + bj[j];
        sv[r][j] = s;
        tm = fmaxf(tm, s);
      }
      tm = fmaxf(tm, __shfl_xor(tm, 1));
      tm = fmaxf(tm, __shfl_xor(tm, 2));
      tm = fmaxf(tm, __shfl_xor(tm, 4));
      tm = fmaxf(tm, __shfl_xor(tm, 8));
      tmax[r] = tm;
      need = fmaxf(need, tm - m[r]);
    }
    if (__any(need > 8.0f)) {           // defer-max (T13)
#pragma unroll
      for (int r = 0; r < 4; ++r) {
        float mn = fmaxf(m[r], tmax[r]);
        float al = __expf(m[r] - mn);
        lsum[r] *= al;
        m[r] = mn;
#pragma unroll
        for (int dt = 0; dt < 4; ++dt) oacc[dt][r] *= al;
      }
    }
#pragma unroll
    for (int r = 0; r < 4; ++r) {
      float rs = 0.f;
#pragma unroll
      for (int j = 0; j < 4; ++j) {
        float pv = __expf(sv[r][j] - m[r]);
        plds[w][g * 4 + r][j * 16 + lr] = f2bf(pv);
        rs += pv;
      }
      rs += __shfl_xor(rs, 1);
      rs += __shfl_xor(rs, 2);
      rs += __shfl_xor(rs, 4);
      rs += __shfl_xor(rs, 8);
      lsum[r] += rs;
    }
    bf16x8 pa0 = ldb8(&plds[w][lr][lk]);
    bf16x8 pa1 = ldb8(&plds[w][lr][32 + lk]);
#pragma unroll
    for (int dt = 0; dt < 4; ++dt) {
      const uint16_t* vr = Vbp + (dt * 16 + lr) * 64;
      oacc[dt] = __builtin_amdgcn_mfma_f32_16x16x32_bf16(pa0, ldb8(vr + koff0), oacc[dt], 0, 0, 0);
      oacc[dt] = __builtin_amdgcn_mfma_f32_16x16x32_bf16(pa1, ldb8(vr + koff1), oacc[dt], 0, 0, 0);
    }
    MEMFENCE;
    __builtin_amdgcn_s_barrier();
  }

  float inv[4];
#pragma unroll
  for (int r = 0; r < 4; ++r) inv[r] = lsum[r] > 0.f ? 1.f / lsum[r] : 0.f;
  uint16_t* ob = o + (size_t)(b * NSEQ + q0) * DMODEL + h * HDIM;
#pragma unroll
  for (int dt = 0; dt < 4; ++dt)
#pragma unroll
    for (int r = 0; r < 4; ++r)
      ob[(size_t)(g * 4 + r) * DMODEL + dt * 16 + lr] = f2bf(oacc[dt][r] * inv[r]);
}

// ---------------- host ----------------
extern "C" void kernel_launch(void* const* d_in, const int* in_sizes, int n_in,
                              void* d_out, int out_size, void* d_ws, size_t ws_size,
                              hipStream_t stream) {
  const float* x      = (const float*)d_in[0];
  const int*   amask  = (const int*)d_in[1];
  const float* ln1_g  = (const float*)d_in[2];
  const float* ln1_b  = (const float*)d_in[3];
  const float* qkv_w  = (const float*)d_in[4];
  const float* q_bias = (const float*)d_in[5];
  const float* v_bias = (const float*)d_in[6];
  const float* proj_w = (const float*)d_in[7];
  const float* proj_b = (const float*)d_in[8];
  const float* ln2_g  = (const float*)d_in[9];
  const float* ln2_b  = (const float*)d_in[10];
  const float* fc1_w  = (const float*)d_in[11];
  const float* fc1_b  = (const float*)d_in[12];
  const float* fc2_w  = (const float*)d_in[13];
  const float* fc2_b  = (const float*)d_in[14];
  const float* g1     = (const float*)d_in[15];
  const float* g2     = (const float*)d_in[16];

  char* ws = (char*)d_ws;
  uint16_t* qkvw_bf  = (uint16_t*)(ws + 0);
  uint16_t* projw_bf = (uint16_t*)(ws + 3538944);
  uint16_t* fc1w_bf  = (uint16_t*)(ws + 4718592);
  uint16_t* fc2w_bf  = (uint16_t*)(ws + 9437184);
  float*    qkvbias  = (float*)(ws + 14155776);
  uint16_t* h_bf     = (uint16_t*)(ws + 14164992);
  uint16_t* qkv_bf   = (uint16_t*)(ws + 20456448);
  uint16_t* vt_bf    = (uint16_t*)(ws + 39330816);
  uint16_t* o_bf     = (uint16_t*)(ws + 45622272);
  float*    x1_f     = (float*)(ws + 51913728);
  uint16_t* fc1_bf   = qkv_bf;
  uint16_t* h2_bf    = h_bf;

  const int M = BATCH * NSEQ;

  cvt4_kernel<<<(N_QKVW + N_PROJW + N_FC1W + N_FC2W) / 1024, 256, 0, stream>>>(
      qkv_w, proj_w, fc1_w, fc2_w, qkvw_bf, projw_bf, fc1w_bf, fc2w_bf);
  bias_kernel<<<(3 * DMODEL + 255) / 256, 256, 0, stream>>>(q_bias, v_bias, qkvbias);

  ln_kernel<<<M, 256, 0, stream>>>(x, ln1_g, ln1_b, h_bf);
  gemm128<0><<<dim3((3 * DMODEL) / 128, M / 128), 256, 0, stream>>>(
      h_bf, qkvw_bf, qkvbias, qkv_bf, nullptr, nullptr, M, 3 * DMODEL, DMODEL);
  vtrans_kernel<<<dim3(BATCH * NHEAD, NSEQ / 64), 256, 0, stream>>>(qkv_bf, vt_bf);
  attn_kernel<<<dim3(BATCH * NHEAD, NSEQ / 64), 256, 0, stream>>>(qkv_bf, vt_bf, amask, o_bf);
  gemm128<1><<<dim3(DMODEL / 128, M / 128), 256, 0, stream>>>(
      o_bf, projw_bf, proj_b, x1_f, x, g1, M, DMODEL, DMODEL);
  ln_kernel<<<M, 256, 0, stream>>>(x1_f, ln2_g, ln2_b, h2_bf);
  gemm128<2><<<dim3(HIDDEN / 128, M / 128), 256, 0, stream>>>(
      h2_bf, fc1w_bf, fc1_b, fc1_bf, nullptr, nullptr, M, HIDDEN, DMODEL);
  gemm128<3><<<dim3(DMODEL / 128, M / 128), 256, 0, stream>>>(
      fc1_bf, fc2w_bf, fc2_b, (float*)d_out, x1_f, g2, M, DMODEL, HIDDEN);
}